// Round 1
// baseline (523.685 us; speedup 1.0000x reference)
//
#include <hip/hip_runtime.h>
#include <hip/hip_bf16.h>

#define NJ 24
#define NV 6890
#define NR (NV*3)       // 20670 rows of the blend output per batch
#define NPF 207         // pose feature dim

__device__ constexpr int PAR[24] = {-1,0,0,0,1,2,3,4,5,6,7,8,9,9,9,12,13,14,16,17,18,19,20,21};

// ---------------- Kernel 1: Rodrigues + pose_feature ----------------
__global__ __launch_bounds__(256) void k_rodrigues(const float* __restrict__ theta,
        float* __restrict__ Rws, float* __restrict__ pfws, int B) {
    int idx = blockIdx.x * blockDim.x + threadIdx.x;   // b*24 + j
    if (idx >= B * NJ) return;
    int b = idx / NJ, j = idx % NJ;
    float x = theta[b*72 + j*3 + 0];
    float y = theta[b*72 + j*3 + 1];
    float z = theta[b*72 + j*3 + 2];
    float n = sqrtf(x*x + y*y + z*z);
    float a = fmaxf(n, 1e-8f);
    float inv = 1.0f / a;
    float ix = x*inv, iy = y*inv, iz = z*inv;
    float c = cosf(a), s = sinf(a), t = 1.0f - c;
    float r[9];
    r[0] = t*ix*ix + c;     r[1] = t*ix*iy - s*iz;  r[2] = t*ix*iz + s*iy;
    r[3] = t*ix*iy + s*iz;  r[4] = t*iy*iy + c;     r[5] = t*iy*iz - s*ix;
    r[6] = t*ix*iz - s*iy;  r[7] = t*iy*iz + s*ix;  r[8] = t*iz*iz + c;
    float* Rp = Rws + (size_t)idx * 9;
    #pragma unroll
    for (int k = 0; k < 9; ++k) Rp[k] = r[k];
    if (j >= 1) {
        float* p = pfws + (size_t)b * NPF + (j-1)*9;
        #pragma unroll
        for (int k = 0; k < 9; ++k) p[k] = r[k] - ((k == 0 || k == 4 || k == 8) ? 1.0f : 0.0f);
    }
}

// ---------------- Kernel 2: v_posed = v_template + beta@sd^T + pf@pd^T ----------------
// block: 256 threads, one row r each, 32 batches per block (batch-tiled so posedirs is reused)
__global__ __launch_bounds__(256) void k_blend(const float* __restrict__ beta,
        const float* __restrict__ sd, const float* __restrict__ pd,
        const float* __restrict__ pfws, const float* __restrict__ vt,
        float* __restrict__ vout, int B) {
    __shared__ float pf_lds[NPF * 32];
    __shared__ float bt_lds[10 * 32];
    int tid = threadIdx.x;
    int b0 = blockIdx.y * 32;
    int r = blockIdx.x * 256 + tid;

    for (int idx = tid; idx < NPF * 32; idx += 256) {
        int k = idx >> 5, bb = idx & 31;
        int b = b0 + bb;
        pf_lds[idx] = (b < B) ? pfws[(size_t)b * NPF + k] : 0.0f;
    }
    for (int idx = tid; idx < 10 * 32; idx += 256) {
        int k = idx >> 5, bb = idx & 31;
        int b = b0 + bb;
        bt_lds[idx] = (b < B) ? beta[(size_t)b * 10 + k] : 0.0f;
    }
    __syncthreads();
    if (r >= NR) return;

    float acc[32];
    #pragma unroll
    for (int i = 0; i < 32; ++i) acc[i] = 0.0f;

    const float* sdr = sd + (size_t)r * 10;
    #pragma unroll
    for (int k = 0; k < 10; ++k) {
        float v = sdr[k];
        const float4* f = (const float4*)&bt_lds[k * 32];
        #pragma unroll
        for (int q = 0; q < 8; ++q) {
            float4 fv = f[q];
            acc[q*4+0] += v * fv.x; acc[q*4+1] += v * fv.y;
            acc[q*4+2] += v * fv.z; acc[q*4+3] += v * fv.w;
        }
    }

    const float* pdr = pd + (size_t)r * NPF;
    #pragma unroll 3
    for (int k = 0; k < NPF; ++k) {
        float v = pdr[k];
        const float4* f = (const float4*)&pf_lds[k * 32];
        #pragma unroll
        for (int q = 0; q < 8; ++q) {
            float4 fv = f[q];
            acc[q*4+0] += v * fv.x; acc[q*4+1] += v * fv.y;
            acc[q*4+2] += v * fv.z; acc[q*4+3] += v * fv.w;
        }
    }

    float vtv = vt[r];
    #pragma unroll
    for (int bb = 0; bb < 32; ++bb) {
        int b = b0 + bb;
        if (b < B) vout[(size_t)b * NR + r] = acc[bb] + vtv;
    }
}

// ---------------- Kernel 3: J[b,j,k] = sum_v Jreg[j,v] * v_posed[b,v,k] ----------------
__global__ __launch_bounds__(256) void k_jreg(const float* __restrict__ vposed,
        const float* __restrict__ Jreg, float* __restrict__ Jout, int B) {
    int b = blockIdx.x;
    int tid = threadIdx.x;
    float acc[72];
    #pragma unroll
    for (int i = 0; i < 72; ++i) acc[i] = 0.0f;
    const float* vp = vposed + (size_t)b * NR;
    for (int v = tid; v < NV; v += 256) {
        float x = vp[v*3+0], y = vp[v*3+1], z = vp[v*3+2];
        #pragma unroll
        for (int j = 0; j < NJ; ++j) {
            float w = Jreg[(size_t)j * NV + v];
            acc[j*3+0] += w * x;
            acc[j*3+1] += w * y;
            acc[j*3+2] += w * z;
        }
    }
    // wave reduce
    #pragma unroll
    for (int i = 0; i < 72; ++i) {
        float s = acc[i];
        #pragma unroll
        for (int off = 32; off > 0; off >>= 1) s += __shfl_down(s, off, 64);
        acc[i] = s;
    }
    __shared__ float red[4 * 72];
    int wave = tid >> 6, lane = tid & 63;
    if (lane == 0) {
        #pragma unroll
        for (int i = 0; i < 72; ++i) red[wave*72 + i] = acc[i];
    }
    __syncthreads();
    if (tid < 72) {
        float s = red[tid] + red[72 + tid] + red[144 + tid] + red[216 + tid];
        Jout[(size_t)b * 72 + tid] = s;
    }
}

// ---------------- Kernel 4: kinematic chain -> G_corr (B,24,12) ----------------
__global__ __launch_bounds__(32) void k_chain(const float* __restrict__ Rg,
        const float* __restrict__ Jg, float* __restrict__ Gc, int B) {
    __shared__ float Gs[32 * 289];   // per-thread 288 floats, stride 289 to avoid bank conflicts
    int b = blockIdx.x * 32 + threadIdx.x;
    if (b >= B) return;
    float* G = &Gs[threadIdx.x * 289];
    float Jl[72];
    const float* Jb = Jg + (size_t)b * 72;
    #pragma unroll
    for (int i = 0; i < 72; ++i) Jl[i] = Jb[i];
    const float* Rb = Rg + (size_t)b * 216;
    // root: G0 = [R0 | J0]
    G[0]=Rb[0]; G[1]=Rb[1]; G[2]=Rb[2];  G[3]=Jl[0];
    G[4]=Rb[3]; G[5]=Rb[4]; G[6]=Rb[5];  G[7]=Jl[1];
    G[8]=Rb[6]; G[9]=Rb[7]; G[10]=Rb[8]; G[11]=Jl[2];
    #pragma unroll
    for (int i = 1; i < NJ; ++i) {
        const int p = PAR[i];
        const float* Ri = Rb + i*9;
        float r00=Ri[0],r01=Ri[1],r02=Ri[2];
        float r10=Ri[3],r11=Ri[4],r12=Ri[5];
        float r20=Ri[6],r21=Ri[7],r22=Ri[8];
        float px=Jl[p*3+0], py=Jl[p*3+1], pz=Jl[p*3+2];
        float tx = Jl[i*3+0] - (r00*px + r01*py + r02*pz);
        float ty = Jl[i*3+1] - (r10*px + r11*py + r12*pz);
        float tz = Jl[i*3+2] - (r20*px + r21*py + r22*pz);
        const float* gp = &G[p*12];
        float* gi = &G[i*12];
        #pragma unroll
        for (int rr = 0; rr < 3; ++rr) {
            float a0=gp[rr*4+0], a1=gp[rr*4+1], a2=gp[rr*4+2], a3=gp[rr*4+3];
            gi[rr*4+0] = a0*r00 + a1*r10 + a2*r20;
            gi[rr*4+1] = a0*r01 + a1*r11 + a2*r21;
            gi[rr*4+2] = a0*r02 + a1*r12 + a2*r22;
            gi[rr*4+3] = a0*tx + a1*ty + a2*tz + a3;
        }
    }
    float* out = Gc + (size_t)b * 288;
    #pragma unroll
    for (int i = 0; i < NJ; ++i) {
        const float* gi = &G[i*12];
        float jx=Jl[i*3+0], jy=Jl[i*3+1], jz=Jl[i*3+2];
        #pragma unroll
        for (int rr = 0; rr < 3; ++rr) {
            out[i*12+rr*4+0] = gi[rr*4+0];
            out[i*12+rr*4+1] = gi[rr*4+1];
            out[i*12+rr*4+2] = gi[rr*4+2];
            out[i*12+rr*4+3] = gi[rr*4+3] - (gi[rr*4+0]*jx + gi[rr*4+1]*jy + gi[rr*4+2]*jz);
        }
    }
}

// ---------------- Kernel 5: skinning, in place on v region of d_out ----------------
__global__ __launch_bounds__(256) void k_skin(float* __restrict__ vio,
        const float* __restrict__ W, const float* __restrict__ Gc, int B) {
    __shared__ float g[288];
    int b = blockIdx.y;
    for (int i = threadIdx.x; i < 288; i += 256) g[i] = Gc[(size_t)b * 288 + i];
    __syncthreads();
    int v = blockIdx.x * 256 + threadIdx.x;
    if (v >= NV) return;
    float* vp = vio + (size_t)b * NR + (size_t)v * 3;
    float x = vp[0], y = vp[1], z = vp[2];
    const float* wr = W + (size_t)v * NJ;
    float T[12];
    #pragma unroll
    for (int t = 0; t < 12; ++t) T[t] = 0.0f;
    #pragma unroll
    for (int j = 0; j < NJ; ++j) {
        float w = wr[j];
        const float* gj = &g[j*12];
        #pragma unroll
        for (int t = 0; t < 12; ++t) T[t] += w * gj[t];
    }
    float ox = T[0]*x + T[1]*y + T[2]*z  + T[3];
    float oy = T[4]*x + T[5]*y + T[6]*z  + T[7];
    float oz = T[8]*x + T[9]*y + T[10]*z + T[11];
    vp[0] = ox; vp[1] = oy; vp[2] = oz;
}

extern "C" void kernel_launch(void* const* d_in, const int* in_sizes, int n_in,
                              void* d_out, int out_size, void* d_ws, size_t ws_size,
                              hipStream_t stream) {
    const float* theta = (const float*)d_in[0];
    const float* beta  = (const float*)d_in[1];
    const float* sd    = (const float*)d_in[2];
    const float* pd    = (const float*)d_in[3];
    const float* Jreg  = (const float*)d_in[4];
    const float* vt    = (const float*)d_in[5];
    const float* W     = (const float*)d_in[6];
    float* out = (float*)d_out;

    const int B = in_sizes[0] / 72;

    // d_out layout: [v_out (B*NR)] [J (B*72)]
    float* vregion = out;                       // also used as v_posed storage (in-place skinning)
    float* Jout    = out + (size_t)B * NR;

    // ws layout (floats): R (B*216) | pf (B*207) | Gc (B*288)
    float* Rws  = (float*)d_ws;
    float* pfws = Rws + (size_t)B * 216;
    float* Gcws = pfws + (size_t)B * NPF;

    // 1. Rodrigues
    {
        int n = B * NJ;
        k_rodrigues<<<(n + 255) / 256, 256, 0, stream>>>(theta, Rws, pfws, B);
    }
    // 2. Blend (writes v_posed into vregion)
    {
        dim3 grid((NR + 255) / 256, (B + 31) / 32);
        k_blend<<<grid, 256, 0, stream>>>(beta, sd, pd, pfws, vt, vregion, B);
    }
    // 3. Joint regression
    k_jreg<<<B, 256, 0, stream>>>(vregion, Jreg, Jout, B);
    // 4. Kinematic chain
    k_chain<<<(B + 31) / 32, 32, 0, stream>>>(Rws, Jout, Gcws, B);
    // 5. Skinning (in place)
    {
        dim3 grid((NV + 255) / 256, B);
        k_skin<<<grid, 256, 0, stream>>>(vregion, W, Gcws, B);
    }
}

// Round 2
// 382.184 us; speedup vs baseline: 1.3702x; 1.3702x over previous
//
#include <hip/hip_runtime.h>
#include <hip/hip_bf16.h>

#define NJ 24
#define NV 6890
#define NR (NV*3)        // 20670 output rows per batch
#define NPF 207          // pose feature dim
#define KB 217           // real K = 207 pf + 10 beta
#define KP 224           // padded K (7 x 32)
#define NRP 20736        // padded N (162*128)
#define LSTR 232         // LDS row stride in bf16 elems (224 + 8 pad)

typedef short s16x8 __attribute__((ext_vector_type(8)));
typedef float f32x4 __attribute__((ext_vector_type(4)));

__device__ constexpr int PAR[24] = {-1,0,0,0,1,2,3,4,5,6,7,8,9,9,9,12,13,14,16,17,18,19,20,21};

__device__ __forceinline__ short f2bf(float f) {
    __hip_bfloat16 h = __float2bfloat16(f);
    return *reinterpret_cast<short*>(&h);
}

// ---------------- Kernel 1: Rodrigues -> R (fp32 ws) + A matrix (bf16: [pf | beta | 0]) ----------------
__global__ __launch_bounds__(256) void k_rodrigues(const float* __restrict__ theta,
        const float* __restrict__ beta,
        float* __restrict__ Rws, short* __restrict__ Aws, int B) {
    int idx = blockIdx.x * blockDim.x + threadIdx.x;   // b*24 + j
    if (idx >= B * NJ) return;
    int b = idx / NJ, j = idx % NJ;
    float x = theta[b*72 + j*3 + 0];
    float y = theta[b*72 + j*3 + 1];
    float z = theta[b*72 + j*3 + 2];
    float n = sqrtf(x*x + y*y + z*z);
    float a = fmaxf(n, 1e-8f);
    float inv = 1.0f / a;
    float ix = x*inv, iy = y*inv, iz = z*inv;
    float c = cosf(a), s = sinf(a), t = 1.0f - c;
    float r[9];
    r[0] = t*ix*ix + c;     r[1] = t*ix*iy - s*iz;  r[2] = t*ix*iz + s*iy;
    r[3] = t*ix*iy + s*iz;  r[4] = t*iy*iy + c;     r[5] = t*iy*iz - s*ix;
    r[6] = t*ix*iz - s*iy;  r[7] = t*iy*iz + s*ix;  r[8] = t*iz*iz + c;
    float* Rp = Rws + (size_t)idx * 9;
    #pragma unroll
    for (int k = 0; k < 9; ++k) Rp[k] = r[k];
    short* Ab = Aws + (size_t)b * KP;
    if (j >= 1) {
        #pragma unroll
        for (int k = 0; k < 9; ++k)
            Ab[(j-1)*9 + k] = f2bf(r[k] - ((k == 0 || k == 4 || k == 8) ? 1.0f : 0.0f));
    } else {
        #pragma unroll
        for (int k = 0; k < 10; ++k) Ab[NPF + k] = f2bf(beta[b*10 + k]);
        #pragma unroll
        for (int k = KB; k < KP; ++k) Ab[k] = 0;
    }
}

// ---------------- Kernel 2: MFMA GEMM  v_posed[b][r] = A[b][:] . B[r][:] + vt[r] ----------------
// A = Aws (B x 224 bf16). B rows built inline from pd (fp32) | sd (fp32) | zeros.
// 128(M=batch) x 128(N=rows) tile, whole K (224) staged in LDS, 4 waves (2x2), 7 k-steps.
__global__ __launch_bounds__(256) void k_gemm(const short* __restrict__ Aws,
        const float* __restrict__ pd, const float* __restrict__ sd,
        const float* __restrict__ vt, float* __restrict__ vout, int B) {
    extern __shared__ short lds[];                  // A: [128][LSTR], B: [128][LSTR]
    short* Alds = lds;
    short* Blds = lds + 128 * LSTR;
    const int t = threadIdx.x;
    const int ntile = blockIdx.x, btile = blockIdx.y;
    const int b0 = btile * 128, r0 = ntile * 128;

    // stage A (bf16 16-B chunks) and B (fp32->bf16 inline), 3584 chunks each
    #pragma unroll
    for (int it = 0; it < 14; ++it) {
        int cidx = it * 256 + t;
        int row = cidx / 28, c = cidx - row * 28;
        int col0 = c * 8;
        // --- A ---
        {
            int bg = b0 + row;
            s16x8 av;
            if (bg < B) {
                av = *(const s16x8*)&Aws[(size_t)bg * KP + col0];
            } else {
                #pragma unroll
                for (int k = 0; k < 8; ++k) av[k] = 0;
            }
            *(s16x8*)&Alds[row * LSTR + col0] = av;
        }
        // --- B ---
        {
            int rg = r0 + row;
            s16x8 bv;
            if (rg < NR) {
                if (col0 + 7 < NPF) {
                    const float* p = pd + (size_t)rg * NPF + col0;
                    #pragma unroll
                    for (int k = 0; k < 8; ++k) bv[k] = f2bf(p[k]);
                } else {
                    #pragma unroll
                    for (int k = 0; k < 8; ++k) {
                        int col = col0 + k;
                        float f = 0.0f;
                        if (col < NPF)      f = pd[(size_t)rg * NPF + col];
                        else if (col < KB)  f = sd[(size_t)rg * 10 + (col - NPF)];
                        bv[k] = f2bf(f);
                    }
                }
            } else {
                #pragma unroll
                for (int k = 0; k < 8; ++k) bv[k] = 0;
            }
            *(s16x8*)&Blds[row * LSTR + col0] = bv;
        }
    }
    __syncthreads();

    const int wave = t >> 6, lane = t & 63;
    const int wm = (wave >> 1) * 64, wn = (wave & 1) * 64;
    const int q = lane >> 4, r16 = lane & 15;

    f32x4 acc[4][4];
    #pragma unroll
    for (int m = 0; m < 4; ++m)
        #pragma unroll
        for (int n = 0; n < 4; ++n)
            #pragma unroll
            for (int i = 0; i < 4; ++i) acc[m][n][i] = 0.0f;

    #pragma unroll
    for (int ks = 0; ks < 7; ++ks) {
        const int koff = ks * 32 + q * 8;
        s16x8 af[4], bf[4];
        #pragma unroll
        for (int m = 0; m < 4; ++m)
            af[m] = *(const s16x8*)&Alds[(wm + m*16 + r16) * LSTR + koff];
        #pragma unroll
        for (int n = 0; n < 4; ++n)
            bf[n] = *(const s16x8*)&Blds[(wn + n*16 + r16) * LSTR + koff];
        #pragma unroll
        for (int m = 0; m < 4; ++m)
            #pragma unroll
            for (int n = 0; n < 4; ++n)
                acc[m][n] = __builtin_amdgcn_mfma_f32_16x16x32_bf16(af[m], bf[n], acc[m][n], 0, 0, 0);
    }

    // epilogue: C/D layout col=lane&15, row=q*4+i
    #pragma unroll
    for (int m = 0; m < 4; ++m) {
        #pragma unroll
        for (int n = 0; n < 4; ++n) {
            int rg = r0 + wn + n*16 + r16;
            #pragma unroll
            for (int i = 0; i < 4; ++i) {
                int bg = b0 + wm + m*16 + q*4 + i;
                if (bg < B && rg < NR)
                    vout[(size_t)bg * NR + rg] = acc[m][n][i] + vt[rg];
            }
        }
    }
}

// ---------------- Kernel 3: J[b,j,k] = sum_v Jreg[j,v] * v_posed[b,v,k] ----------------
__global__ __launch_bounds__(256) void k_jreg(const float* __restrict__ vposed,
        const float* __restrict__ Jreg, float* __restrict__ Jout, int B) {
    int b = blockIdx.x;
    int tid = threadIdx.x;
    float acc[72];
    #pragma unroll
    for (int i = 0; i < 72; ++i) acc[i] = 0.0f;
    const float* vp = vposed + (size_t)b * NR;
    for (int v = tid; v < NV; v += 256) {
        float x = vp[v*3+0], y = vp[v*3+1], z = vp[v*3+2];
        #pragma unroll
        for (int j = 0; j < NJ; ++j) {
            float w = Jreg[(size_t)j * NV + v];
            acc[j*3+0] += w * x;
            acc[j*3+1] += w * y;
            acc[j*3+2] += w * z;
        }
    }
    #pragma unroll
    for (int i = 0; i < 72; ++i) {
        float s = acc[i];
        #pragma unroll
        for (int off = 32; off > 0; off >>= 1) s += __shfl_down(s, off, 64);
        acc[i] = s;
    }
    __shared__ float red[4 * 72];
    int wave = tid >> 6, lane = tid & 63;
    if (lane == 0) {
        #pragma unroll
        for (int i = 0; i < 72; ++i) red[wave*72 + i] = acc[i];
    }
    __syncthreads();
    if (tid < 72) {
        float s = red[tid] + red[72 + tid] + red[144 + tid] + red[216 + tid];
        Jout[(size_t)b * 72 + tid] = s;
    }
}

// ---------------- Kernel 4: kinematic chain -> G_corr (B,24,12) ----------------
__global__ __launch_bounds__(32) void k_chain(const float* __restrict__ Rg,
        const float* __restrict__ Jg, float* __restrict__ Gc, int B) {
    __shared__ float Gs[32 * 289];
    int b = blockIdx.x * 32 + threadIdx.x;
    if (b >= B) return;
    float* G = &Gs[threadIdx.x * 289];
    float Jl[72];
    const float* Jb = Jg + (size_t)b * 72;
    #pragma unroll
    for (int i = 0; i < 72; ++i) Jl[i] = Jb[i];
    const float* Rb = Rg + (size_t)b * 216;
    G[0]=Rb[0]; G[1]=Rb[1]; G[2]=Rb[2];  G[3]=Jl[0];
    G[4]=Rb[3]; G[5]=Rb[4]; G[6]=Rb[5];  G[7]=Jl[1];
    G[8]=Rb[6]; G[9]=Rb[7]; G[10]=Rb[8]; G[11]=Jl[2];
    #pragma unroll
    for (int i = 1; i < NJ; ++i) {
        const int p = PAR[i];
        const float* Ri = Rb + i*9;
        float r00=Ri[0],r01=Ri[1],r02=Ri[2];
        float r10=Ri[3],r11=Ri[4],r12=Ri[5];
        float r20=Ri[6],r21=Ri[7],r22=Ri[8];
        float px=Jl[p*3+0], py=Jl[p*3+1], pz=Jl[p*3+2];
        float tx = Jl[i*3+0] - (r00*px + r01*py + r02*pz);
        float ty = Jl[i*3+1] - (r10*px + r11*py + r12*pz);
        float tz = Jl[i*3+2] - (r20*px + r21*py + r22*pz);
        const float* gp = &G[p*12];
        float* gi = &G[i*12];
        #pragma unroll
        for (int rr = 0; rr < 3; ++rr) {
            float a0=gp[rr*4+0], a1=gp[rr*4+1], a2=gp[rr*4+2], a3=gp[rr*4+3];
            gi[rr*4+0] = a0*r00 + a1*r10 + a2*r20;
            gi[rr*4+1] = a0*r01 + a1*r11 + a2*r21;
            gi[rr*4+2] = a0*r02 + a1*r12 + a2*r22;
            gi[rr*4+3] = a0*tx + a1*ty + a2*tz + a3;
        }
    }
    float* out = Gc + (size_t)b * 288;
    #pragma unroll
    for (int i = 0; i < NJ; ++i) {
        const float* gi = &G[i*12];
        float jx=Jl[i*3+0], jy=Jl[i*3+1], jz=Jl[i*3+2];
        #pragma unroll
        for (int rr = 0; rr < 3; ++rr) {
            out[i*12+rr*4+0] = gi[rr*4+0];
            out[i*12+rr*4+1] = gi[rr*4+1];
            out[i*12+rr*4+2] = gi[rr*4+2];
            out[i*12+rr*4+3] = gi[rr*4+3] - (gi[rr*4+0]*jx + gi[rr*4+1]*jy + gi[rr*4+2]*jz);
        }
    }
}

// ---------------- Kernel 5: skinning, 8 batches per block, in place ----------------
__global__ __launch_bounds__(256) void k_skin(float* __restrict__ vio,
        const float* __restrict__ W, const float* __restrict__ Gc, int B) {
    __shared__ float g[8 * 288];
    int b0 = blockIdx.y * 8;
    for (int i = threadIdx.x; i < 8 * 288; i += 256) g[i] = Gc[(size_t)b0 * 288 + i];
    __syncthreads();
    int v = blockIdx.x * 256 + threadIdx.x;
    if (v >= NV) return;
    float w[NJ];
    const float* wr = W + (size_t)v * NJ;
    #pragma unroll
    for (int j = 0; j < NJ; ++j) w[j] = wr[j];
    #pragma unroll 2
    for (int bb = 0; bb < 8; ++bb) {
        int b = b0 + bb;
        if (b >= B) break;
        float* vp = vio + (size_t)b * NR + (size_t)v * 3;
        float x = vp[0], y = vp[1], z = vp[2];
        const float* gb = &g[bb * 288];
        float T[12];
        #pragma unroll
        for (int tt = 0; tt < 12; ++tt) T[tt] = 0.0f;
        #pragma unroll
        for (int j = 0; j < NJ; ++j) {
            float wj = w[j];
            const float* gj = &gb[j*12];
            #pragma unroll
            for (int tt = 0; tt < 12; ++tt) T[tt] += wj * gj[tt];
        }
        vp[0] = T[0]*x + T[1]*y + T[2]*z  + T[3];
        vp[1] = T[4]*x + T[5]*y + T[6]*z  + T[7];
        vp[2] = T[8]*x + T[9]*y + T[10]*z + T[11];
    }
}

extern "C" void kernel_launch(void* const* d_in, const int* in_sizes, int n_in,
                              void* d_out, int out_size, void* d_ws, size_t ws_size,
                              hipStream_t stream) {
    const float* theta = (const float*)d_in[0];
    const float* beta  = (const float*)d_in[1];
    const float* sd    = (const float*)d_in[2];
    const float* pd    = (const float*)d_in[3];
    const float* Jreg  = (const float*)d_in[4];
    const float* vt    = (const float*)d_in[5];
    const float* W     = (const float*)d_in[6];
    float* out = (float*)d_out;

    const int B = in_sizes[0] / 72;

    float* vregion = out;                        // v_posed then v_out (in-place skin)
    float* Jout    = out + (size_t)B * NR;

    // ws (bytes): Rws B*216 f32 | Gc B*288 f32 | Aws B*224 bf16   (~2.5 MB, proven available)
    float* Rws  = (float*)d_ws;
    float* Gcws = Rws + (size_t)B * 216;
    short* Aws  = (short*)(Gcws + (size_t)B * 288);

    // 1. Rodrigues + A matrix
    {
        int n = B * NJ;
        k_rodrigues<<<(n + 255) / 256, 256, 0, stream>>>(theta, beta, Rws, Aws, B);
    }
    // 2. MFMA blend GEMM -> v_posed (fp32, +v_template)
    {
        dim3 grid(NRP / 128, (B + 127) / 128);
        size_t shmem = (size_t)2 * 128 * LSTR * sizeof(short);   // 118,784 B
        k_gemm<<<grid, 256, shmem, stream>>>(Aws, pd, sd, vt, vregion, B);
    }
    // 3. Joint regression
    k_jreg<<<B, 256, 0, stream>>>(vregion, Jreg, Jout, B);
    // 4. Kinematic chain
    k_chain<<<(B + 31) / 32, 32, 0, stream>>>(Rws, Jout, Gcws, B);
    // 5. Skinning (in place, 8 batches/block)
    {
        dim3 grid((NV + 255) / 256, (B + 7) / 8);
        k_skin<<<grid, 256, 0, stream>>>(vregion, W, Gcws, B);
    }
}

// Round 3
// 290.605 us; speedup vs baseline: 1.8020x; 1.3151x over previous
//
#include <hip/hip_runtime.h>
#include <hip/hip_bf16.h>

#define NJ 24
#define NV 6890
#define NR (NV*3)        // 20670 output rows per batch
#define NPF 207
#define KB 217           // 207 pf + 10 beta
#define KP 256           // padded K (8 x 32)
#define NT 162           // n-tiles (162*128 = 20736 >= NR)
#define NRP (NT*128)
#define NSPLIT 128       // jdirs v-splits
#define VPB 54           // ceil(6890/128)

typedef short s16x8 __attribute__((ext_vector_type(8)));
typedef float f32x4 __attribute__((ext_vector_type(4)));

__device__ constexpr int PAR[24] = {-1,0,0,0,1,2,3,4,5,6,7,8,9,9,9,12,13,14,16,17,18,19,20,21};

__device__ __forceinline__ short f2bf(float f) {
    __hip_bfloat16 h = __float2bfloat16(f);
    return *reinterpret_cast<short*>(&h);
}

// ============ K1: Rodrigues -> Rws(f32), pfA(f32 plain), Atiles(bf16 swizzled) ============
__global__ __launch_bounds__(256) void k_rodrigues(const float* __restrict__ theta,
        const float* __restrict__ beta, float* __restrict__ Rws,
        float* __restrict__ pfA, short* __restrict__ Atiles, int B) {
    int idx = blockIdx.x * blockDim.x + threadIdx.x;   // b*24 + j
    if (idx >= B * NJ) return;
    int b = idx / NJ, j = idx % NJ;
    float x = theta[b*72 + j*3 + 0];
    float y = theta[b*72 + j*3 + 1];
    float z = theta[b*72 + j*3 + 2];
    float n = sqrtf(x*x + y*y + z*z);
    float a = fmaxf(n, 1e-8f);
    float inv = 1.0f / a;
    float ix = x*inv, iy = y*inv, iz = z*inv;
    float c = cosf(a), s = sinf(a), t = 1.0f - c;
    float r[9];
    r[0] = t*ix*ix + c;     r[1] = t*ix*iy - s*iz;  r[2] = t*ix*iz + s*iy;
    r[3] = t*ix*iy + s*iz;  r[4] = t*iy*iy + c;     r[5] = t*iy*iz - s*ix;
    r[6] = t*ix*iz - s*iy;  r[7] = t*iy*iz + s*ix;  r[8] = t*iz*iz + c;
    float* Rp = Rws + (size_t)idx * 9;
    #pragma unroll
    for (int k = 0; k < 9; ++k) Rp[k] = r[k];

    int rb = b & 127;
    int hs = (rb >> 1) & 7;
    short* At = Atiles + (size_t)(b >> 7) * (128*KP) + (size_t)rb * KP;
    float* pa = pfA + (size_t)b * 224;
    if (j >= 1) {
        #pragma unroll
        for (int kk = 0; kk < 9; ++kk) {
            int k = (j-1)*9 + kk;
            float f = r[kk] - ((kk == 0 || kk == 4 || kk == 8) ? 1.0f : 0.0f);
            At[(((k>>3) ^ hs) << 3) + (k & 7)] = f2bf(f);
            pa[k] = f;
        }
    } else {
        #pragma unroll
        for (int kk = 0; kk < 10; ++kk) {
            int k = NPF + kk;
            float f = beta[b*10 + kk];
            At[(((k>>3) ^ hs) << 3) + (k & 7)] = f2bf(f);
            pa[k] = f;
        }
        for (int k = KB; k < KP; ++k)
            At[(((k>>3) ^ hs) << 3) + (k & 7)] = 0;
    }
}

// ============ K2: build Btiles (bf16, tile-contiguous, chunk-swizzled) ============
// tile nt: rows rg=nt*128..+127, row r holds cols 0..255 = [pd(207) | sd(10) | 0]
__global__ __launch_bounds__(256) void k_convB(const float* __restrict__ pd,
        const float* __restrict__ sd, short* __restrict__ Btiles) {
    int idx = blockIdx.x * 256 + threadIdx.x;          // (rg, chunk)
    int rg = idx >> 5, c = idx & 31;
    int r = rg & 127, nt = rg >> 7;
    s16x8 v;
    if (rg < NR) {
        int k0 = c * 8;
        if (k0 + 7 < NPF) {
            const float* p = pd + (size_t)rg * NPF + k0;
            #pragma unroll
            for (int k = 0; k < 8; ++k) v[k] = f2bf(p[k]);
        } else {
            #pragma unroll
            for (int k = 0; k < 8; ++k) {
                int col = k0 + k;
                float f = 0.0f;
                if (col < NPF)     f = pd[(size_t)rg * NPF + col];
                else if (col < KB) f = sd[(size_t)rg * 10 + (col - NPF)];
                v[k] = f2bf(f);
            }
        }
    } else {
        #pragma unroll
        for (int k = 0; k < 8; ++k) v[k] = 0;
    }
    int csw = c ^ ((r >> 1) & 7);
    *(s16x8*)&Btiles[(size_t)nt * (128*KP) + (size_t)r * KP + csw * 8] = v;
}

// ============ K3: JD partials: part[bi][k][jc] = sum_{v in split} Jreg[j,v]*col_k(row v*3+c) ============
__global__ __launch_bounds__(256) void k_jdirs(const float* __restrict__ pd,
        const float* __restrict__ sd, const float* __restrict__ vt,
        const float* __restrict__ Jreg, float* __restrict__ part) {
    int k = threadIdx.x;
    int bi = blockIdx.x;
    int v0 = bi * VPB, v1 = min(NV, v0 + VPB);
    float acc[72];
    #pragma unroll
    for (int i = 0; i < 72; ++i) acc[i] = 0.0f;
    for (int v = v0; v < v1; ++v) {
        float w[24];
        #pragma unroll
        for (int j = 0; j < 24; ++j) w[j] = Jreg[(size_t)j * NV + v];
        #pragma unroll
        for (int c = 0; c < 3; ++c) {
            int row = v*3 + c;
            float val = 0.0f;
            if (k < NPF)      val = pd[(size_t)row * NPF + k];
            else if (k < KB)  val = sd[(size_t)row * 10 + (k - NPF)];
            else if (k == KB) val = vt[row];
            #pragma unroll
            for (int j = 0; j < 24; ++j) acc[j*3 + c] += w[j] * val;
        }
    }
    if (k <= KB) {
        float* p = part + ((size_t)bi * 224 + k) * 72;
        #pragma unroll
        for (int i = 0; i < 72; ++i) p[i] = acc[i];
    }
}

// ============ K4: reduce partials -> JDt[k][72] (k=0..217; 217 = vt column) ============
__global__ __launch_bounds__(256) void k_jreduce(const float* __restrict__ part,
        float* __restrict__ JDt) {
    int e = blockIdx.x * 256 + threadIdx.x;
    if (e >= 218 * 72) return;
    float s = 0.0f;
    #pragma unroll 4
    for (int bi = 0; bi < NSPLIT; ++bi) s += part[(size_t)bi * (224*72) + e];
    JDt[e] = s;
}

// ============ K5: J[b][jc] = JDt[217][jc] + sum_k pfA[b][k]*JDt[k][jc] ============
__global__ __launch_bounds__(128) void k_J(const float* __restrict__ pfA,
        const float* __restrict__ JDt, float* __restrict__ Jout, int B) {
    int b = blockIdx.x, t = threadIdx.x;
    if (t >= 72) return;
    const float* pa = pfA + (size_t)b * 224;
    float acc = JDt[217*72 + t];
    #pragma unroll 7
    for (int k = 0; k < KB; ++k) acc += pa[k] * JDt[k*72 + t];
    Jout[(size_t)b * 72 + t] = acc;
}

// ============ K6: MFMA GEMM  v_posed = A(Bx256) . B^T + vt ============
// 128x128 tile, whole K in LDS via linear global_load_lds of pre-swizzled tiles.
__global__ __launch_bounds__(256) void k_gemm(const short* __restrict__ At,
        const short* __restrict__ Bt, const float* __restrict__ vt,
        float* __restrict__ vout, int B) {
    extern __shared__ short lds[];                 // [A 32768][B 32768] shorts
    const int t = threadIdx.x;
    const int nt = blockIdx.x, bt = blockIdx.y;
    const int wave = t >> 6, lane = t & 63;
    const short* Asrc = At + (size_t)bt * (128*KP);
    const short* Bsrc = Bt + (size_t)nt * (128*KP);

    #pragma unroll
    for (int it = 0; it < 16; ++it) {
        int seg = (it * 4 + wave) * 512;           // shorts (1 KiB per wave-chunk)
        __builtin_amdgcn_global_load_lds(Asrc + seg + lane*8, lds + seg, 16, 0, 0);
    }
    #pragma unroll
    for (int it = 0; it < 16; ++it) {
        int seg = (it * 4 + wave) * 512;
        __builtin_amdgcn_global_load_lds(Bsrc + seg + lane*8, lds + 32768 + seg, 16, 0, 0);
    }
    asm volatile("s_waitcnt vmcnt(0)");
    __syncthreads();

    const int wm = (wave >> 1) * 64, wn = (wave & 1) * 64;
    const int q = lane >> 4, r16 = lane & 15;
    const int hs = (r16 >> 1) & 7;

    f32x4 acc[4][4];
    #pragma unroll
    for (int m = 0; m < 4; ++m)
        #pragma unroll
        for (int n = 0; n < 4; ++n)
            #pragma unroll
            for (int i = 0; i < 4; ++i) acc[m][n][i] = 0.0f;

    #pragma unroll
    for (int ks = 0; ks < 8; ++ks) {
        const int csw = (((ks*4 + q) ^ hs)) * 8;
        s16x8 af[4], bf[4];
        #pragma unroll
        for (int m = 0; m < 4; ++m)
            af[m] = *(const s16x8*)(lds + (wm + m*16 + r16) * KP + csw);
        #pragma unroll
        for (int n = 0; n < 4; ++n)
            bf[n] = *(const s16x8*)(lds + 32768 + (wn + n*16 + r16) * KP + csw);
        #pragma unroll
        for (int m = 0; m < 4; ++m)
            #pragma unroll
            for (int n = 0; n < 4; ++n)
                acc[m][n] = __builtin_amdgcn_mfma_f32_16x16x32_bf16(af[m], bf[n], acc[m][n], 0, 0, 0);
    }

    #pragma unroll
    for (int n = 0; n < 4; ++n) {
        int rg = nt*128 + wn + n*16 + r16;
        bool ok = rg < NR;
        float vtv = ok ? vt[rg] : 0.0f;
        #pragma unroll
        for (int m = 0; m < 4; ++m) {
            #pragma unroll
            for (int i = 0; i < 4; ++i) {
                int bg = bt*128 + wm + m*16 + q*4 + i;
                if (ok && bg < B)
                    vout[(size_t)bg * NR + rg] = acc[m][n][i] + vtv;
            }
        }
    }
}

// ============ K7: kinematic chain -> G_corr (B,24,12) ============
__global__ __launch_bounds__(32) void k_chain(const float* __restrict__ Rg,
        const float* __restrict__ Jg, float* __restrict__ Gc, int B) {
    __shared__ float Gs[32 * 289];
    int b = blockIdx.x * 32 + threadIdx.x;
    if (b >= B) return;
    float* G = &Gs[threadIdx.x * 289];
    float Jl[72];
    const float* Jb = Jg + (size_t)b * 72;
    #pragma unroll
    for (int i = 0; i < 72; ++i) Jl[i] = Jb[i];
    const float* Rb = Rg + (size_t)b * 216;
    G[0]=Rb[0]; G[1]=Rb[1]; G[2]=Rb[2];  G[3]=Jl[0];
    G[4]=Rb[3]; G[5]=Rb[4]; G[6]=Rb[5];  G[7]=Jl[1];
    G[8]=Rb[6]; G[9]=Rb[7]; G[10]=Rb[8]; G[11]=Jl[2];
    #pragma unroll
    for (int i = 1; i < NJ; ++i) {
        const int p = PAR[i];
        const float* Ri = Rb + i*9;
        float r00=Ri[0],r01=Ri[1],r02=Ri[2];
        float r10=Ri[3],r11=Ri[4],r12=Ri[5];
        float r20=Ri[6],r21=Ri[7],r22=Ri[8];
        float px=Jl[p*3+0], py=Jl[p*3+1], pz=Jl[p*3+2];
        float tx = Jl[i*3+0] - (r00*px + r01*py + r02*pz);
        float ty = Jl[i*3+1] - (r10*px + r11*py + r12*pz);
        float tz = Jl[i*3+2] - (r20*px + r21*py + r22*pz);
        const float* gp = &G[p*12];
        float* gi = &G[i*12];
        #pragma unroll
        for (int rr = 0; rr < 3; ++rr) {
            float a0=gp[rr*4+0], a1=gp[rr*4+1], a2=gp[rr*4+2], a3=gp[rr*4+3];
            gi[rr*4+0] = a0*r00 + a1*r10 + a2*r20;
            gi[rr*4+1] = a0*r01 + a1*r11 + a2*r21;
            gi[rr*4+2] = a0*r02 + a1*r12 + a2*r22;
            gi[rr*4+3] = a0*tx + a1*ty + a2*tz + a3;
        }
    }
    float* out = Gc + (size_t)b * 288;
    #pragma unroll
    for (int i = 0; i < NJ; ++i) {
        const float* gi = &G[i*12];
        float jx=Jl[i*3+0], jy=Jl[i*3+1], jz=Jl[i*3+2];
        #pragma unroll
        for (int rr = 0; rr < 3; ++rr) {
            out[i*12+rr*4+0] = gi[rr*4+0];
            out[i*12+rr*4+1] = gi[rr*4+1];
            out[i*12+rr*4+2] = gi[rr*4+2];
            out[i*12+rr*4+3] = gi[rr*4+3] - (gi[rr*4+0]*jx + gi[rr*4+1]*jy + gi[rr*4+2]*jz);
        }
    }
}

// ============ K8: skinning, 8 batches per block, in place ============
__global__ __launch_bounds__(256) void k_skin(float* __restrict__ vio,
        const float* __restrict__ W, const float* __restrict__ Gc, int B) {
    __shared__ float g[8 * 288];
    int b0 = blockIdx.y * 8;
    for (int i = threadIdx.x; i < 8 * 288; i += 256) g[i] = Gc[(size_t)b0 * 288 + i];
    __syncthreads();
    int v = blockIdx.x * 256 + threadIdx.x;
    if (v >= NV) return;
    float w[NJ];
    const float4* wr4 = (const float4*)(W + (size_t)v * NJ);
    #pragma unroll
    for (int u = 0; u < 6; ++u) {
        float4 f = wr4[u];
        w[u*4+0]=f.x; w[u*4+1]=f.y; w[u*4+2]=f.z; w[u*4+3]=f.w;
    }
    #pragma unroll 2
    for (int bb = 0; bb < 8; ++bb) {
        int b = b0 + bb;
        if (b >= B) break;
        float* vp = vio + (size_t)b * NR + (size_t)v * 3;
        float x = vp[0], y = vp[1], z = vp[2];
        const float* gb = &g[bb * 288];
        float T[12];
        #pragma unroll
        for (int tt = 0; tt < 12; ++tt) T[tt] = 0.0f;
        #pragma unroll
        for (int j = 0; j < NJ; ++j) {
            float wj = w[j];
            const float* gj = &gb[j*12];
            #pragma unroll
            for (int tt = 0; tt < 12; ++tt) T[tt] += wj * gj[tt];
        }
        vp[0] = T[0]*x + T[1]*y + T[2]*z  + T[3];
        vp[1] = T[4]*x + T[5]*y + T[6]*z  + T[7];
        vp[2] = T[8]*x + T[9]*y + T[10]*z + T[11];
    }
}

extern "C" void kernel_launch(void* const* d_in, const int* in_sizes, int n_in,
                              void* d_out, int out_size, void* d_ws, size_t ws_size,
                              hipStream_t stream) {
    const float* theta = (const float*)d_in[0];
    const float* beta  = (const float*)d_in[1];
    const float* sd    = (const float*)d_in[2];
    const float* pd    = (const float*)d_in[3];
    const float* Jreg  = (const float*)d_in[4];
    const float* vt    = (const float*)d_in[5];
    const float* W     = (const float*)d_in[6];
    float* out = (float*)d_out;

    const int B = in_sizes[0] / 72;

    float* vregion = out;                         // scratch until k_gemm, then v_posed/v_out
    float* Jout    = out + (size_t)B * NR;

    // ws layout (all 16B-aligned): Rws | Gc | pfA | Atiles | Btiles  (~13.5 MB)
    float* Rws   = (float*)d_ws;                          // B*216 f32
    float* Gcws  = Rws + (size_t)B * 216;                 // B*288 f32
    float* pfA   = Gcws + (size_t)B * 288;                // B*224 f32
    short* Atile = (short*)(pfA + (size_t)B * 224);       // (B/128)*128*256 bf16
    short* Btile = Atile + (size_t)(B/128) * 128 * KP;    // 162*128*256 bf16

    // d_out v-region doubles as scratch before k_gemm overwrites it:
    float* part = vregion;                                // NSPLIT*224*72 f32 (~8.3 MB)
    float* JDt  = vregion + (size_t)NSPLIT * 224 * 72;    // 224*72 f32

    // 1. Rodrigues -> Rws, pfA, Atile
    k_rodrigues<<<(B*NJ + 255)/256, 256, 0, stream>>>(theta, beta, Rws, pfA, Atile, B);
    // 2. Btiles (bf16 swizzled)
    k_convB<<<(NRP*32)/256, 256, 0, stream>>>(pd, sd, Btile);
    // 3-4. JD = Jreg-regressed dirs (partials in d_out scratch, then reduce)
    k_jdirs<<<NSPLIT, 256, 0, stream>>>(pd, sd, vt, Jreg, part);
    k_jreduce<<<(218*72 + 255)/256, 256, 0, stream>>>(part, JDt);
    // 5. J = Jt + pfA . JD   (writes J output region)
    k_J<<<B, 128, 0, stream>>>(pfA, JDt, Jout, B);
    // 6. kinematic chain -> G_corr
    k_chain<<<(B + 31)/32, 32, 0, stream>>>(Rws, Jout, Gcws, B);
    // 7. blend GEMM -> v_posed (overwrites scratch region)
    {
        dim3 grid(NT, B/128);
        k_gemm<<<grid, 256, 131072, stream>>>(Atile, Btile, vt, vregion, B);
    }
    // 8. skinning in place
    {
        dim3 grid((NV + 255)/256, (B + 7)/8);
        k_skin<<<grid, 256, 0, stream>>>(vregion, W, Gcws, B);
    }
}

// Round 4
// 204.768 us; speedup vs baseline: 2.5575x; 1.4192x over previous
//
#include <hip/hip_runtime.h>
#include <hip/hip_bf16.h>

#define NJ 24
#define NV 6890
#define NR (NV*3)        // 20670 output rows per batch
#define NPF 207
#define KB 217           // 207 pf + 10 beta
#define KP 256           // padded K (8 x 32)
#define NT 162           // n-tiles (162*128 = 20736 >= NR)
#define NRP (NT*128)
#define NSPLIT 128       // jdirs v-splits
#define VPB 54           // ceil(6890/128)

typedef short s16x8 __attribute__((ext_vector_type(8)));
typedef float f32x4 __attribute__((ext_vector_type(4)));

__device__ constexpr int PAR[24] = {-1,0,0,0,1,2,3,4,5,6,7,8,9,9,9,12,13,14,16,17,18,19,20,21};

__device__ __forceinline__ short f2bf(float f) {
    __hip_bfloat16 h = __float2bfloat16(f);
    return *reinterpret_cast<short*>(&h);
}

// ============ K1: Rodrigues -> Rws(f32), pfA(f32 plain), Atiles(bf16 swizzled) ============
__global__ __launch_bounds__(256) void k_rodrigues(const float* __restrict__ theta,
        const float* __restrict__ beta, float* __restrict__ Rws,
        float* __restrict__ pfA, short* __restrict__ Atiles, int B) {
    int idx = blockIdx.x * blockDim.x + threadIdx.x;   // b*24 + j
    if (idx >= B * NJ) return;
    int b = idx / NJ, j = idx % NJ;
    float x = theta[b*72 + j*3 + 0];
    float y = theta[b*72 + j*3 + 1];
    float z = theta[b*72 + j*3 + 2];
    float n = sqrtf(x*x + y*y + z*z);
    float a = fmaxf(n, 1e-8f);
    float inv = 1.0f / a;
    float ix = x*inv, iy = y*inv, iz = z*inv;
    float c = cosf(a), s = sinf(a), t = 1.0f - c;
    float r[9];
    r[0] = t*ix*ix + c;     r[1] = t*ix*iy - s*iz;  r[2] = t*ix*iz + s*iy;
    r[3] = t*ix*iy + s*iz;  r[4] = t*iy*iy + c;     r[5] = t*iy*iz - s*ix;
    r[6] = t*ix*iz - s*iy;  r[7] = t*iy*iz + s*ix;  r[8] = t*iz*iz + c;
    float* Rp = Rws + (size_t)idx * 9;
    #pragma unroll
    for (int k = 0; k < 9; ++k) Rp[k] = r[k];

    int rb = b & 127;
    int hs = (rb >> 1) & 7;
    short* At = Atiles + (size_t)(b >> 7) * (128*KP) + (size_t)rb * KP;
    float* pa = pfA + (size_t)b * 224;
    if (j >= 1) {
        #pragma unroll
        for (int kk = 0; kk < 9; ++kk) {
            int k = (j-1)*9 + kk;
            float f = r[kk] - ((kk == 0 || kk == 4 || kk == 8) ? 1.0f : 0.0f);
            At[(((k>>3) ^ hs) << 3) + (k & 7)] = f2bf(f);
            pa[k] = f;
        }
    } else {
        #pragma unroll
        for (int kk = 0; kk < 10; ++kk) {
            int k = NPF + kk;
            float f = beta[b*10 + kk];
            At[(((k>>3) ^ hs) << 3) + (k & 7)] = f2bf(f);
            pa[k] = f;
        }
        for (int k = KB; k < KP; ++k)
            At[(((k>>3) ^ hs) << 3) + (k & 7)] = 0;
    }
}

// ============ K2: build Btiles (bf16, tile-contiguous, chunk-swizzled) ============
__global__ __launch_bounds__(256) void k_convB(const float* __restrict__ pd,
        const float* __restrict__ sd, short* __restrict__ Btiles) {
    int idx = blockIdx.x * 256 + threadIdx.x;          // (rg, chunk)
    int rg = idx >> 5, c = idx & 31;
    int r = rg & 127, nt = rg >> 7;
    s16x8 v;
    if (rg < NR) {
        int k0 = c * 8;
        if (k0 + 7 < NPF) {
            const float* p = pd + (size_t)rg * NPF + k0;
            #pragma unroll
            for (int k = 0; k < 8; ++k) v[k] = f2bf(p[k]);
        } else {
            #pragma unroll
            for (int k = 0; k < 8; ++k) {
                int col = k0 + k;
                float f = 0.0f;
                if (col < NPF)     f = pd[(size_t)rg * NPF + col];
                else if (col < KB) f = sd[(size_t)rg * 10 + (col - NPF)];
                v[k] = f2bf(f);
            }
        }
    } else {
        #pragma unroll
        for (int k = 0; k < 8; ++k) v[k] = 0;
    }
    int csw = c ^ ((r >> 1) & 7);
    *(s16x8*)&Btiles[(size_t)nt * (128*KP) + (size_t)r * KP + csw * 8] = v;
}

// ============ K3: JD partials ============
__global__ __launch_bounds__(256) void k_jdirs(const float* __restrict__ pd,
        const float* __restrict__ sd, const float* __restrict__ vt,
        const float* __restrict__ Jreg, float* __restrict__ part) {
    int k = threadIdx.x;
    int bi = blockIdx.x;
    int v0 = bi * VPB, v1 = min(NV, v0 + VPB);
    float acc[72];
    #pragma unroll
    for (int i = 0; i < 72; ++i) acc[i] = 0.0f;
    for (int v = v0; v < v1; ++v) {
        float w[24];
        #pragma unroll
        for (int j = 0; j < 24; ++j) w[j] = Jreg[(size_t)j * NV + v];
        #pragma unroll
        for (int c = 0; c < 3; ++c) {
            int row = v*3 + c;
            float val = 0.0f;
            if (k < NPF)      val = pd[(size_t)row * NPF + k];
            else if (k < KB)  val = sd[(size_t)row * 10 + (k - NPF)];
            else if (k == KB) val = vt[row];
            #pragma unroll
            for (int j = 0; j < 24; ++j) acc[j*3 + c] += w[j] * val;
        }
    }
    if (k <= KB) {
        float* p = part + ((size_t)bi * 224 + k) * 72;
        #pragma unroll
        for (int i = 0; i < 72; ++i) p[i] = acc[i];
    }
}

// ============ K4: reduce partials -> JDt[k][72] ============
__global__ __launch_bounds__(256) void k_jreduce(const float* __restrict__ part,
        float* __restrict__ JDt) {
    int e = blockIdx.x * 256 + threadIdx.x;
    if (e >= 218 * 72) return;
    float s = 0.0f;
    #pragma unroll 4
    for (int bi = 0; bi < NSPLIT; ++bi) s += part[(size_t)bi * (224*72) + e];
    JDt[e] = s;
}

// ============ K5: J[b][jc] = JDt[217][jc] + sum_k pfA[b][k]*JDt[k][jc] ============
__global__ __launch_bounds__(128) void k_J(const float* __restrict__ pfA,
        const float* __restrict__ JDt, float* __restrict__ Jout, int B) {
    int b = blockIdx.x, t = threadIdx.x;
    if (t >= 72) return;
    const float* pa = pfA + (size_t)b * 224;
    float acc = JDt[217*72 + t];
    #pragma unroll 7
    for (int k = 0; k < KB; ++k) acc += pa[k] * JDt[k*72 + t];
    Jout[(size_t)b * 72 + t] = acc;
}

// ============ K6: MFMA GEMM, 64-KB LDS (two K-halves through one buffer) ============
__global__ __launch_bounds__(256) void k_gemm(const short* __restrict__ At,
        const short* __restrict__ Bt, const float* __restrict__ vt,
        float* __restrict__ vout, int B) {
    extern __shared__ short lds[];                 // A half: 16384 shorts, B half: 16384
    short* ldsA = lds;
    short* ldsB = lds + 16384;
    const int t = threadIdx.x;
    const int nt = blockIdx.x, bt = blockIdx.y;
    const int wave = t >> 6, lane = t & 63;
    const int lrow = lane >> 4, lcol = lane & 15;  // staging: 4 rows x 128 shorts per instr
    const short* Asrc = At + (size_t)bt * (128*KP);
    const short* Bsrc = Bt + (size_t)nt * (128*KP);

    const int wm = (wave >> 1) * 64, wn = (wave & 1) * 64;
    const int q = lane >> 4, r16 = lane & 15;
    const int hs = (r16 >> 1) & 7;

    f32x4 acc[4][4];
    #pragma unroll
    for (int m = 0; m < 4; ++m)
        #pragma unroll
        for (int n = 0; n < 4; ++n)
            #pragma unroll
            for (int i = 0; i < 4; ++i) acc[m][n][i] = 0.0f;

    #pragma unroll
    for (int h = 0; h < 2; ++h) {
        // stage half h: rows copy verbatim (swizzle is closed within each 16-chunk half)
        #pragma unroll
        for (int it = 0; it < 8; ++it) {
            int seg = (it * 4 + wave) * 512;       // shorts; = r0*128
            int r0 = (it * 4 + wave) * 4;
            __builtin_amdgcn_global_load_lds(
                Asrc + (size_t)(r0 + lrow) * KP + h * 128 + lcol * 8,
                ldsA + seg, 16, 0, 0);
        }
        #pragma unroll
        for (int it = 0; it < 8; ++it) {
            int seg = (it * 4 + wave) * 512;
            int r0 = (it * 4 + wave) * 4;
            __builtin_amdgcn_global_load_lds(
                Bsrc + (size_t)(r0 + lrow) * KP + h * 128 + lcol * 8,
                ldsB + seg, 16, 0, 0);
        }
        asm volatile("s_waitcnt vmcnt(0)");
        __syncthreads();

        #pragma unroll
        for (int ksl = 0; ksl < 4; ++ksl) {
            const int csw = ((ksl*4 + q) ^ hs) * 8;
            s16x8 af[4], bf[4];
            #pragma unroll
            for (int m = 0; m < 4; ++m)
                af[m] = *(const s16x8*)(ldsA + (wm + m*16 + r16) * 128 + csw);
            #pragma unroll
            for (int n = 0; n < 4; ++n)
                bf[n] = *(const s16x8*)(ldsB + (wn + n*16 + r16) * 128 + csw);
            #pragma unroll
            for (int m = 0; m < 4; ++m)
                #pragma unroll
                for (int n = 0; n < 4; ++n)
                    acc[m][n] = __builtin_amdgcn_mfma_f32_16x16x32_bf16(af[m], bf[n], acc[m][n], 0, 0, 0);
        }
        __syncthreads();   // before overwriting buffer with half 1
    }

    #pragma unroll
    for (int n = 0; n < 4; ++n) {
        int rg = nt*128 + wn + n*16 + r16;
        bool ok = rg < NR;
        float vtv = ok ? vt[rg] : 0.0f;
        #pragma unroll
        for (int m = 0; m < 4; ++m) {
            #pragma unroll
            for (int i = 0; i < 4; ++i) {
                int bg = bt*128 + wm + m*16 + q*4 + i;
                if (ok && bg < B)
                    vout[(size_t)bg * NR + rg] = acc[m][n][i] + vtv;
            }
        }
    }
}

// ============ K7: kinematic chain -> G_corr (B,24,12) ============
__global__ __launch_bounds__(32) void k_chain(const float* __restrict__ Rg,
        const float* __restrict__ Jg, float* __restrict__ Gc, int B) {
    __shared__ float Gs[32 * 289];
    int b = blockIdx.x * 32 + threadIdx.x;
    if (b >= B) return;
    float* G = &Gs[threadIdx.x * 289];
    float Jl[72];
    const float* Jb = Jg + (size_t)b * 72;
    #pragma unroll
    for (int i = 0; i < 72; ++i) Jl[i] = Jb[i];
    const float* Rb = Rg + (size_t)b * 216;
    G[0]=Rb[0]; G[1]=Rb[1]; G[2]=Rb[2];  G[3]=Jl[0];
    G[4]=Rb[3]; G[5]=Rb[4]; G[6]=Rb[5];  G[7]=Jl[1];
    G[8]=Rb[6]; G[9]=Rb[7]; G[10]=Rb[8]; G[11]=Jl[2];
    #pragma unroll
    for (int i = 1; i < NJ; ++i) {
        const int p = PAR[i];
        const float* Ri = Rb + i*9;
        float r00=Ri[0],r01=Ri[1],r02=Ri[2];
        float r10=Ri[3],r11=Ri[4],r12=Ri[5];
        float r20=Ri[6],r21=Ri[7],r22=Ri[8];
        float px=Jl[p*3+0], py=Jl[p*3+1], pz=Jl[p*3+2];
        float tx = Jl[i*3+0] - (r00*px + r01*py + r02*pz);
        float ty = Jl[i*3+1] - (r10*px + r11*py + r12*pz);
        float tz = Jl[i*3+2] - (r20*px + r21*py + r22*pz);
        const float* gp = &G[p*12];
        float* gi = &G[i*12];
        #pragma unroll
        for (int rr = 0; rr < 3; ++rr) {
            float a0=gp[rr*4+0], a1=gp[rr*4+1], a2=gp[rr*4+2], a3=gp[rr*4+3];
            gi[rr*4+0] = a0*r00 + a1*r10 + a2*r20;
            gi[rr*4+1] = a0*r01 + a1*r11 + a2*r21;
            gi[rr*4+2] = a0*r02 + a1*r12 + a2*r22;
            gi[rr*4+3] = a0*tx + a1*ty + a2*tz + a3;
        }
    }
    float* out = Gc + (size_t)b * 288;
    #pragma unroll
    for (int i = 0; i < NJ; ++i) {
        const float* gi = &G[i*12];
        float jx=Jl[i*3+0], jy=Jl[i*3+1], jz=Jl[i*3+2];
        #pragma unroll
        for (int rr = 0; rr < 3; ++rr) {
            out[i*12+rr*4+0] = gi[rr*4+0];
            out[i*12+rr*4+1] = gi[rr*4+1];
            out[i*12+rr*4+2] = gi[rr*4+2];
            out[i*12+rr*4+3] = gi[rr*4+3] - (gi[rr*4+0]*jx + gi[rr*4+1]*jy + gi[rr*4+2]*jz);
        }
    }
}

// ============ K8: MFMA skinning ============
// Per batch: C[comp][vert] = Gm(16x32) . W^T  via one 16x16x32 MFMA per 16 verts.
// Lane (q, c): holds T[q*4+0..3] of vert c -> out comp q = acc.(x,y,z)*vh + acc[3].
__global__ __launch_bounds__(256) void k_skin(float* __restrict__ vio,
        const float* __restrict__ W, const float* __restrict__ Gc, int B) {
    __shared__ short Gm[16 * 40];      // [comp][joint], stride 40, zero-padded
    const int t = threadIdx.x;
    const int wave = t >> 6, lane = t & 63;
    const int q = lane >> 4, c = lane & 15;
    const int vb = blockIdx.x * 256 + wave * 64;
    const int b0 = blockIdx.y * 8;

    if (t < 320) ((int*)Gm)[t] = 0;    // zero all 640 shorts once (pads stay 0)

    // W fragments: bf[m] = bf16 W[vert(m,c)][q*8..+7], q==3 -> K-pad zeros. Reused all batches.
    s16x8 wf[4];
    #pragma unroll
    for (int m = 0; m < 4; ++m) {
        int vert = vb + m*16 + c;
        if (q < 3 && vert < NV) {
            const float* wp = W + (size_t)vert * NJ + q*8;
            float4 f0 = *(const float4*)(wp);
            float4 f1 = *(const float4*)(wp + 4);
            wf[m][0]=f2bf(f0.x); wf[m][1]=f2bf(f0.y); wf[m][2]=f2bf(f0.z); wf[m][3]=f2bf(f0.w);
            wf[m][4]=f2bf(f1.x); wf[m][5]=f2bf(f1.y); wf[m][6]=f2bf(f1.z); wf[m][7]=f2bf(f1.w);
        } else {
            #pragma unroll
            for (int e = 0; e < 8; ++e) wf[m][e] = 0;
        }
    }
    __syncthreads();

    for (int bb = 0; bb < 8; ++bb) {
        int b = b0 + bb;
        // stage Gm[comp][j] = bf16(Gc[b*288 + j*12 + comp]) — linear coalesced source read
        {
            int i0 = t;
            int j0 = i0 / 12, c0 = i0 - j0*12;
            if (i0 < 288) Gm[c0*40 + j0] = f2bf(Gc[(size_t)b*288 + i0]);
            int i1 = t + 256;
            if (i1 < 288) {
                int j1 = i1 / 12, c1 = i1 - j1*12;
                Gm[c1*40 + j1] = f2bf(Gc[(size_t)b*288 + i1]);
            }
        }
        __syncthreads();

        s16x8 af = *(const s16x8*)&Gm[c*40 + q*8];
        #pragma unroll
        for (int m = 0; m < 4; ++m) {
            f32x4 zz = {0.0f, 0.0f, 0.0f, 0.0f};
            f32x4 acc = __builtin_amdgcn_mfma_f32_16x16x32_bf16(af, wf[m], zz, 0, 0, 0);
            int vert = vb + m*16 + c;
            bool ok = (q < 3) && (vert < NV);
            if (ok) {
                float* vp = vio + (size_t)b * NR + (size_t)vert * 3;
                float x = vp[0], y = vp[1], z = vp[2];
                float o = acc[0]*x + acc[1]*y + acc[2]*z + acc[3];
                vp[q] = o;
            }
        }
        __syncthreads();   // af reads done before next batch's staging overwrite
    }
}

extern "C" void kernel_launch(void* const* d_in, const int* in_sizes, int n_in,
                              void* d_out, int out_size, void* d_ws, size_t ws_size,
                              hipStream_t stream) {
    const float* theta = (const float*)d_in[0];
    const float* beta  = (const float*)d_in[1];
    const float* sd    = (const float*)d_in[2];
    const float* pd    = (const float*)d_in[3];
    const float* Jreg  = (const float*)d_in[4];
    const float* vt    = (const float*)d_in[5];
    const float* W     = (const float*)d_in[6];
    float* out = (float*)d_out;

    const int B = in_sizes[0] / 72;

    float* vregion = out;
    float* Jout    = out + (size_t)B * NR;

    float* Rws   = (float*)d_ws;                          // B*216 f32
    float* Gcws  = Rws + (size_t)B * 216;                 // B*288 f32
    float* pfA   = Gcws + (size_t)B * 288;                // B*224 f32
    short* Atile = (short*)(pfA + (size_t)B * 224);       // (B/128)*128*256 bf16
    short* Btile = Atile + (size_t)(B/128) * 128 * KP;    // 162*128*256 bf16

    float* part = vregion;                                // d_out scratch pre-GEMM
    float* JDt  = vregion + (size_t)NSPLIT * 224 * 72;

    k_rodrigues<<<(B*NJ + 255)/256, 256, 0, stream>>>(theta, beta, Rws, pfA, Atile, B);
    k_convB<<<(NRP*32)/256, 256, 0, stream>>>(pd, sd, Btile);
    k_jdirs<<<NSPLIT, 256, 0, stream>>>(pd, sd, vt, Jreg, part);
    k_jreduce<<<(218*72 + 255)/256, 256, 0, stream>>>(part, JDt);
    k_J<<<B, 128, 0, stream>>>(pfA, JDt, Jout, B);
    k_chain<<<(B + 31)/32, 32, 0, stream>>>(Rws, Jout, Gcws, B);
    {
        dim3 grid(NT, B/128);
        k_gemm<<<grid, 256, 65536, stream>>>(Atile, Btile, vt, vregion, B);
    }
    {
        dim3 grid((NV + 255)/256, (B + 7)/8);
        k_skin<<<grid, 256, 0, stream>>>(vregion, W, Gcws, B);
    }
}